// Round 1
// 745.989 us; speedup vs baseline: 1.0593x; 1.0593x over previous
//
#include <hip/hip_runtime.h>

// JTNNVAE message-passing net on MI355X — round 5.
// r4 counters showed prologue (the longest dispatch) with MfmaUtil 7.8 / VALUBusy 9.7 /
// HBM 25% / occ 37% and VGPR_Count=56: VMEM-latency-serialized, ~1 load in flight/wave.
// r5: (1) swap MFMA operands (A=W-frag from LDS, B=edge-row frag) — load addresses are
// unchanged (A/B frag layouts are symmetric for 16x16x32), but the D-layout transposes so
// each lane owns ONE edge row and 4-consecutive cols per frag. A column permutation phi
// folded into weight prep (WhT_swz / WiT only; g/tb/t3/t4 stay logical) makes each lane's
// frag-pair land on 8 contiguous cols -> epilogues become 4x16B stores (was 32x2B) and
// mp_iter's tb read 4x16B loads (was 32x2B). (2) explicit prefetch: prologue hoists all 8
// t3 frags into av[8] before phase X; mp_iter prefetches tbv[4] + double-buffers the 3
// pred-row loads one K-step ahead. Same numerics as r4 (same sums, same order).
// ws: WhT_swz 128K | WiT 32K | WoT1 32K | WoT2 128K | tb 102.4M | gA 102.4M | gB 102.4M
// (t3 aliases gB) | optional t4 25.6M.

#define H 256

typedef __attribute__((ext_vector_type(4))) float f32x4;
typedef __attribute__((ext_vector_type(8))) short bf16x8;

#define MFMA(a, b, c) __builtin_amdgcn_mfma_f32_16x16x32_bf16((a), (b), (c), 0, 0, 0)

__device__ __forceinline__ float bf2f(ushort u) {
  union { unsigned int i; float f; } v; v.i = ((unsigned int)u) << 16; return v.f;
}
__device__ __forceinline__ ushort f2bf(float f) {
  union { float f; unsigned int i; } v; v.f = f;
  unsigned int i = v.i;
  i += 0x7fffu + ((i >> 16) & 1u);   // RNE
  return (ushort)(i >> 16);
}

union AFrag { bf16x8 v; ushort u[8]; };

__device__ __forceinline__ int edge_delta(int o) {
  return ((o & 2) ? 5 : 1) * ((o & 1) ? -1 : 1);   // o=0:+1 1:-1 2:+5 3:-5
}

// phi: logical col L -> storage position w in WhT_swz/WiT for the swapped-operand MFMA.
// With D-layout value (nf=2t+h, kg, j) coming from W position colbase+32t+16h+4kg+j,
// phi makes that value's LOGICAL col equal colbase+32t+8kg+4h+j — i.e. lane kg's pair of
// frags (2t, 2t+1) covers 8 contiguous logical cols, enabling one 16B store.
__device__ __forceinline__ int phi(int L) {
  return (L & ~31) | (((L >> 2) & 1) << 4) | (((L >> 3) & 3) << 2) | (L & 3);
}

// ---------------- weight prep ----------------
__global__ __launch_bounds__(256) void prep_weights_kernel(
    const float* __restrict__ Wh, const float* __restrict__ Wi, const float* __restrict__ Wo,
    ushort* __restrict__ WhT_swz, ushort* __restrict__ WiT,
    ushort* __restrict__ WoT1, ushort* __restrict__ WoT2) {
  const int nn = blockIdx.x;   // logical output col 0..255
  const int t = threadIdx.x;   // K index 0..255
  const int w = phi(nn);       // storage position (permuted within each 32-col block)
  WhT_swz[w * H + (t ^ ((w & 7) << 3))] = f2bf(Wh[t * H + nn]);
  WoT2[nn * H + t] = f2bf(Wo[(35 + t) * H + nn]);   // readout is NOT swapped: unchanged
  if (t < 64) {
    WiT[w * 64 + t] = (t < 40) ? f2bf(Wi[t * H + nn]) : (ushort)0;
    WoT1[nn * 64 + t] = (t < 35) ? f2bf(Wo[t * H + nn]) : (ushort)0;
  }
}

// ---------------- sum_tm: t3[4s+o] = sum_{a != o^1} t_m[inc_a(s)], t4[s] = sum_all -------
__global__ __launch_bounds__(256) void sum_tm_kernel(
    const float* __restrict__ t_m, ushort* __restrict__ t3, ushort* __restrict__ t4,
    int n, int useT4) {
  const int idx = blockIdx.x * 256 + threadIdx.x;
  const int s = idx >> 5;             // 32 col-groups of 8 per row
  if (s >= n) return;
  const int cg = (idx & 31) * 8;
  int im1 = s - 1; if (im1 < 0) im1 += n;
  int ip1 = s + 1; if (ip1 >= n) ip1 -= n;
  int im5 = s - 5; if (im5 < 0) im5 += n;
  int ip5 = s + 5; if (ip5 >= n) ip5 -= n;
  const size_t e0 = (size_t)(4 * im1 + 0) * H + cg;
  const size_t e1 = (size_t)(4 * ip1 + 1) * H + cg;
  const size_t e2 = (size_t)(4 * im5 + 2) * H + cg;
  const size_t e3 = (size_t)(4 * ip5 + 3) * H + cg;
  f32x4 v0a = *(const f32x4*)(t_m + e0), v0b = *(const f32x4*)(t_m + e0 + 4);
  f32x4 v1a = *(const f32x4*)(t_m + e1), v1b = *(const f32x4*)(t_m + e1 + 4);
  f32x4 v2a = *(const f32x4*)(t_m + e2), v2b = *(const f32x4*)(t_m + e2 + 4);
  f32x4 v3a = *(const f32x4*)(t_m + e3), v3b = *(const f32x4*)(t_m + e3 + 4);
  f32x4 Sa = v0a + v1a + v2a + v3a;
  f32x4 Sb = v0b + v1b + v2b + v3b;
  f32x4 ra[4] = {Sa - v1a, Sa - v0a, Sa - v3a, Sa - v2a};
  f32x4 rb[4] = {Sb - v1b, Sb - v0b, Sb - v3b, Sb - v2b};
#pragma unroll
  for (int o = 0; o < 4; ++o) {
    AFrag a;
#pragma unroll
    for (int i = 0; i < 4; ++i) { a.u[i] = f2bf(ra[o][i]); a.u[4 + i] = f2bf(rb[o][i]); }
    *(bf16x8*)(t3 + (size_t)(4 * s + o) * H + cg) = a.v;
  }
  if (useT4) {
    AFrag a;
#pragma unroll
    for (int i = 0; i < 4; ++i) { a.u[i] = f2bf(Sa[i]); a.u[4 + i] = f2bf(Sb[i]); }
    *(bf16x8*)(t4 + (size_t)s * H + cg) = a.v;
  }
}

// ---------------- prologue: tb = x_edges@W_i + t3@W_h ; g0P = relu(binput) ---------------
__global__ __launch_bounds__(512, 4) void prologue_kernel(
    const float* __restrict__ x_edges, const ushort* __restrict__ t3,
    const ushort* __restrict__ WhT_swz, const ushort* __restrict__ WiT,
    ushort* __restrict__ tb, ushort* __restrict__ g0P, int E, int n) {
  extern __shared__ ushort lds[];          // 128 cols x 256 K of WhT_swz (64 KB)
  const int tid = threadIdx.x;
  const int wid = tid >> 6, lane = tid & 63, l15 = lane & 15, kg = lane >> 4;
  const int ch = blockIdx.x >> 8;
  const int colbase = ch << 7;

  {
    const bf16x8* src = (const bf16x8*)(WhT_swz + (size_t)colbase * H);
    bf16x8* dstl = (bf16x8*)lds;
#pragma unroll
    for (int j = 0; j < 8; ++j) dstl[tid + j * 512] = src[tid + j * 512];
  }
  __syncthreads();

  const int nchunks = (E + 127) >> 7;
  for (int c = blockIdx.x & 255; c < nchunks; c += 256) {
    const int row0 = (c << 7) + wid * 16;
    if (row0 >= E) continue;
    const int r = row0 + l15;            // this lane's edge row (swapped D-layout)

    // ---- issue ALL global loads for this chunk up front (MLP) ----
    const float* xp = x_edges + (size_t)r * 40;
    f32x4 xa0 = *(const f32x4*)(xp + kg * 8);
    f32x4 xa1 = *(const f32x4*)(xp + kg * 8 + 4);
    f32x4 xb0, xb1;
    if (kg == 0) { xb0 = *(const f32x4*)(xp + 32); xb1 = *(const f32x4*)(xp + 36); }

    bf16x8 av[8];                        // 8 t3 B-frags in flight across phase X
#pragma unroll
    for (int ks = 0; ks < 8; ++ks)
      av[ks] = *(const bf16x8*)(t3 + (size_t)r * H + ks * 32 + kg * 8);

    f32x4 acc[8];
#pragma unroll
    for (int i = 0; i < 8; ++i) acc[i] = (f32x4){0.f, 0.f, 0.f, 0.f};

    // ---- phase X: binput = x_edges @ W_i, K=40 (padded 64), swapped operands ----
    AFrag bx0, bx1;
#pragma unroll
    for (int i = 0; i < 4; ++i) { bx0.u[i] = f2bf(xa0[i]); bx0.u[4 + i] = f2bf(xa1[i]); }
    if (kg == 0) {
#pragma unroll
      for (int i = 0; i < 4; ++i) { bx1.u[i] = f2bf(xb0[i]); bx1.u[4 + i] = f2bf(xb1[i]); }
    } else {
#pragma unroll
      for (int i = 0; i < 8; ++i) bx1.u[i] = 0;
    }
#pragma unroll
    for (int nf = 0; nf < 8; ++nf) {
      const int w = colbase + nf * 16 + l15;
      bf16x8 a0 = *(const bf16x8*)(WiT + w * 64 + kg * 8);
      acc[nf] = MFMA(a0, bx0.v, acc[nf]);
      bf16x8 a1 = *(const bf16x8*)(WiT + w * 64 + 32 + kg * 8);
      acc[nf] = MFMA(a1, bx1.v, acc[nf]);
    }

    // ---- g0P = relu(binput), permuted row, 4 x 16B stores ----
    const int s_ = r >> 2, o_ = r & 3;
    int d_ = s_ + edge_delta(o_);
    if (d_ < 0) d_ += n; else if (d_ >= n) d_ -= n;
    ushort* gout = g0P + (size_t)(4 * d_ + o_) * H + colbase + kg * 8;
#pragma unroll
    for (int tt = 0; tt < 4; ++tt) {
      AFrag pk;
#pragma unroll
      for (int i = 0; i < 4; ++i) {
        pk.u[i]     = f2bf(fmaxf(acc[2 * tt][i], 0.f));
        pk.u[4 + i] = f2bf(fmaxf(acc[2 * tt + 1][i], 0.f));
      }
      *(bf16x8*)(gout + tt * 32) = pk.v;
    }

    // ---- phase T: += t3 @ W_h (A from LDS, B = prefetched av[]) ----
#pragma unroll
    for (int ks = 0; ks < 8; ++ks) {
      const int k = ks * 32 + kg * 8;
#pragma unroll
      for (int nf = 0; nf < 8; ++nf) {
        const int colloc = nf * 16 + l15;
        bf16x8 a = *(const bf16x8*)(lds + colloc * H + (k ^ ((colloc & 7) << 3)));
        acc[nf] = MFMA(a, av[ks], acc[nf]);
      }
    }

    // ---- tb in ORIGINAL edge order, 4 x 16B stores ----
    ushort* tbp = tb + (size_t)r * H + colbase + kg * 8;
#pragma unroll
    for (int tt = 0; tt < 4; ++tt) {
      AFrag pk;
#pragma unroll
      for (int i = 0; i < 4; ++i) {
        pk.u[i]     = f2bf(acc[2 * tt][i]);
        pk.u[4 + i] = f2bf(acc[2 * tt + 1][i]);
      }
      *(bf16x8*)(tbp + tt * 32) = pk.v;
    }
  }
}

// ---------------- loop body: gNewP = relu(tb + sum_preds(gOldP @ W_h)) --------------------
__global__ __launch_bounds__(512, 4) void mp_iter_kernel(
    const ushort* __restrict__ gOldP, const ushort* __restrict__ tb,
    const ushort* __restrict__ WhT_swz, ushort* __restrict__ gNewP, int E, int n) {
  extern __shared__ ushort lds[];
  const int tid = threadIdx.x;
  const int wid = tid >> 6, lane = tid & 63, l15 = lane & 15, kg = lane >> 4;
  const int ch = blockIdx.x >> 8;
  const int colbase = ch << 7;

  {
    const bf16x8* src = (const bf16x8*)(WhT_swz + (size_t)colbase * H);
    bf16x8* dstl = (bf16x8*)lds;
#pragma unroll
    for (int j = 0; j < 8; ++j) dstl[tid + j * 512] = src[tid + j * 512];
  }
  __syncthreads();

  const int nchunks = (E + 127) >> 7;
  for (int c = blockIdx.x & 255; c < nchunks; c += 256) {
    const int row0 = (c << 7) + wid * 16;
    if (row0 >= E) continue;
    const int r = row0 + l15;
    const int s = r >> 2, o = r & 3, drop = o ^ 1;
    const int a0 = (drop == 0) ? 1 : 0;
    const int a1 = 1 + (drop <= 1);
    const int a2 = 2 + (drop <= 2);
    const ushort* b0 = gOldP + (size_t)(4 * s + a0) * H + kg * 8;
    const ushort* b1 = gOldP + (size_t)(4 * s + a1) * H + kg * 8;
    const ushort* b2 = gOldP + (size_t)(4 * s + a2) * H + kg * 8;

    // prefetch tb (only needed in epilogue) — 4 x 16B, in flight across all MFMAs
    bf16x8 tbv[4];
    const ushort* tbp = tb + (size_t)r * H + colbase + kg * 8;
#pragma unroll
    for (int tt = 0; tt < 4; ++tt) tbv[tt] = *(const bf16x8*)(tbp + tt * 32);

    // double-buffered pred-row loads: ks+1's 3 loads issue before ks's MFMAs retire
    bf16x8 p0[2], p1[2], p2[2];
    p0[0] = *(const bf16x8*)(b0);
    p1[0] = *(const bf16x8*)(b1);
    p2[0] = *(const bf16x8*)(b2);

    f32x4 acc[8];
#pragma unroll
    for (int i = 0; i < 8; ++i) acc[i] = (f32x4){0.f, 0.f, 0.f, 0.f};

#pragma unroll
    for (int ks = 0; ks < 8; ++ks) {
      const int cur = ks & 1, nxt = cur ^ 1;
      if (ks < 7) {
        const int k2 = (ks + 1) * 32;
        p0[nxt] = *(const bf16x8*)(b0 + k2);
        p1[nxt] = *(const bf16x8*)(b1 + k2);
        p2[nxt] = *(const bf16x8*)(b2 + k2);
      }
      const int k = ks * 32 + kg * 8;
#pragma unroll
      for (int nf = 0; nf < 8; ++nf) {
        const int colloc = nf * 16 + l15;
        bf16x8 a = *(const bf16x8*)(lds + colloc * H + (k ^ ((colloc & 7) << 3)));
        f32x4 u = MFMA(a, p0[cur], acc[nf]);
        u = MFMA(a, p1[cur], u);
        acc[nf] = MFMA(a, p2[cur], u);
      }
    }

    int d = s + edge_delta(o);
    if (d < 0) d += n; else if (d >= n) d -= n;
    ushort* gout = gNewP + (size_t)(4 * d + o) * H + colbase + kg * 8;
#pragma unroll
    for (int tt = 0; tt < 4; ++tt) {
      AFrag pk;
#pragma unroll
      for (int i = 0; i < 4; ++i) {
        float v0 = bf2f((ushort)tbv[tt][i])     + acc[2 * tt][i];
        float v1 = bf2f((ushort)tbv[tt][4 + i]) + acc[2 * tt + 1][i];
        pk.u[i]     = f2bf(fmaxf(v0, 0.f));
        pk.u[4 + i] = f2bf(fmaxf(v1, 0.f));
      }
      *(bf16x8*)(gout + tt * 32) = pk.v;
    }
  }
}

// ---------------- readout: per-graph mean of relu([x_nodes, nei]@W_o + b_o) ---------------
__global__ __launch_bounds__(256) void readout_kernel(
    const float* __restrict__ x_nodes, const float* __restrict__ t_m,
    const ushort* __restrict__ gP, const ushort* __restrict__ t4,
    const float* __restrict__ b_o,
    const ushort* __restrict__ WoT1, const ushort* __restrict__ WoT2,
    float* __restrict__ out, int n, int npg, int useT4) {
  const int gidx = blockIdx.x;
  const int wid = threadIdx.x >> 6;
  const int lane = threadIdx.x & 63;
  const int l15 = lane & 15;
  const int kg = lane >> 4;
  const int u0 = gidx * npg;

  __shared__ float red[H];

  f32x4 acc[2][16];
#pragma unroll
  for (int m = 0; m < 2; ++m)
#pragma unroll
    for (int i = 0; i < 16; ++i) acc[m][i] = (f32x4){0.f, 0.f, 0.f, 0.f};

  int uu[2]; bool mv[2]; int inc[2][4];
#pragma unroll
  for (int m = 0; m < 2; ++m) {
    const int mf = wid * 2 + m;
    const int rl = mf * 16 + l15;
    mv[m] = rl < npg;
    const int u = u0 + rl;
    uu[m] = u;
    if (mv[m]) {
      inc[m][0] = 4 * ((u - 1 + n) % n);
      inc[m][1] = 4 * ((u + 1) % n) + 1;
      inc[m][2] = 4 * ((u - 5 + n) % n) + 2;
      inc[m][3] = 4 * ((u + 5) % n) + 3;
    } else {
      inc[m][0] = inc[m][1] = inc[m][2] = inc[m][3] = 0;
    }
  }

  // phase 1: x_nodes part, K=35 (padded 64)
#pragma unroll
  for (int ks = 0; ks < 2; ++ks) {
    const int k = ks * 32 + kg * 8;
#pragma unroll
    for (int m = 0; m < 2; ++m) {
      AFrag a;
#pragma unroll
      for (int i = 0; i < 8; ++i) {
        const int kk = k + i;
        a.u[i] = (mv[m] && kk < 35) ? f2bf(x_nodes[(size_t)uu[m] * 35 + kk]) : (ushort)0;
      }
#pragma unroll
      for (int nf = 0; nf < 16; ++nf) {
        bf16x8 b = *(const bf16x8*)(WoT1 + (nf * 16 + l15) * 64 + k);
        acc[m][nf] = MFMA(a.v, b, acc[m][nf]);
      }
    }
  }

  // phase 2: nei part, K=256.  nei[u] = sum_j gP[4u+j] + (t4[u] | sum_j t_m[inc_j(u)])
#pragma unroll
  for (int ks = 0; ks < 8; ++ks) {
    const int k = ks * 32 + kg * 8;
#pragma unroll
    for (int m = 0; m < 2; ++m) {
      AFrag a;
      if (mv[m]) {
        float s[8];
#pragma unroll
        for (int i = 0; i < 8; ++i) s[i] = 0.f;
        const int e4 = 4 * uu[m];
#pragma unroll
        for (int j = 0; j < 4; ++j) {
          bf16x8 gv = *(const bf16x8*)(gP + (size_t)(e4 + j) * H + k);
#pragma unroll
          for (int i = 0; i < 8; ++i) s[i] += bf2f((ushort)gv[i]);
        }
        if (useT4) {
          bf16x8 tv = *(const bf16x8*)(t4 + (size_t)uu[m] * H + k);
#pragma unroll
          for (int i = 0; i < 8; ++i) s[i] += bf2f((ushort)tv[i]);
        } else {
#pragma unroll
          for (int j = 0; j < 4; ++j) {
            const float* tp = t_m + (size_t)inc[m][j] * H + k;
            f32x4 t0 = *(const f32x4*)tp;
            f32x4 t1 = *(const f32x4*)(tp + 4);
#pragma unroll
            for (int i = 0; i < 4; ++i) { s[i] += t0[i]; s[4 + i] += t1[i]; }
          }
        }
#pragma unroll
        for (int i = 0; i < 8; ++i) a.u[i] = f2bf(s[i]);
      } else {
#pragma unroll
        for (int i = 0; i < 8; ++i) a.u[i] = 0;
      }
#pragma unroll
      for (int nf = 0; nf < 16; ++nf) {
        bf16x8 b = *(const bf16x8*)(WoT2 + (nf * 16 + l15) * H + k);
        acc[m][nf] = MFMA(a.v, b, acc[m][nf]);
      }
    }
  }

  red[threadIdx.x] = 0.f;
  __syncthreads();

#pragma unroll
  for (int nf = 0; nf < 16; ++nf) {
    const int col = nf * 16 + l15;
    const float bias = b_o[col];
    float cs = 0.f;
#pragma unroll
    for (int m = 0; m < 2; ++m) {
#pragma unroll
      for (int j = 0; j < 4; ++j) {
        const int rr = (wid * 2 + m) * 16 + kg * 4 + j;
        if (rr < npg) cs += fmaxf(acc[m][nf][j] + bias, 0.f);
      }
    }
    cs += __shfl_xor(cs, 16);
    cs += __shfl_xor(cs, 32);
    if (kg == 0) atomicAdd(&red[col], cs);
  }
  __syncthreads();
  out[(size_t)gidx * H + threadIdx.x] = red[threadIdx.x] * (1.0f / (float)npg);
}

// ------------------------------------- launch ---------------------------------------------
extern "C" void kernel_launch(void* const* d_in, const int* in_sizes, int n_in,
                              void* d_out, int out_size, void* d_ws, size_t ws_size,
                              hipStream_t stream) {
  const float* x_nodes = (const float*)d_in[0];
  const float* x_edges = (const float*)d_in[1];
  const float* t_m     = (const float*)d_in[2];
  const float* W_i     = (const float*)d_in[3];
  const float* W_h     = (const float*)d_in[4];
  const float* W_o     = (const float*)d_in[5];
  const float* b_o     = (const float*)d_in[6];
  (void)n_in;

  const int n = in_sizes[0] / 35;       // 50000
  const int E = in_sizes[1] / 40;       // 200000
  const int num_graphs = out_size / H;  // 500
  const int npg = n / num_graphs;       // 100

  char* ws = (char*)d_ws;
  ushort* WhT_swz = (ushort*)(ws);              // 131072 B
  ushort* WiT  = (ushort*)(ws + 131072);        // 32768 B
  ushort* WoT1 = (ushort*)(ws + 164 * 1024);    // 32768 B
  ushort* WoT2 = (ushort*)(ws + 200 * 1024);    // 131072 B
  size_t off = 336 * 1024;
  const size_t gbytes = (size_t)E * H * 2;      // 102,400,000
  ushort* tb = (ushort*)(ws + off); off += gbytes;
  ushort* gA = (ushort*)(ws + off); off += gbytes;
  ushort* gB = (ushort*)(ws + off); off += gbytes;
  ushort* t3 = gB;   // t3 only needed until the first mp_iter overwrites gB
  const size_t t4bytes = (size_t)n * H * 2;     // 25,600,000
  const int useT4 = (ws_size >= off + t4bytes) ? 1 : 0;
  ushort* t4 = (ushort*)(ws + off);             // valid only if useT4

  prep_weights_kernel<<<256, 256, 0, stream>>>(W_h, W_i, W_o, WhT_swz, WiT, WoT1, WoT2);
  sum_tm_kernel<<<(n * 32 + 255) / 256, 256, 0, stream>>>(t_m, t3, t4, n, useT4);
  prologue_kernel<<<512, 512, 65536, stream>>>(x_edges, t3, WhT_swz, WiT, tb, gA, E, n);

  ushort* src = gA;
  ushort* dst = gB;
  for (int it = 0; it < 5; ++it) {  // DEPTH-1 = 5
    mp_iter_kernel<<<512, 512, 65536, stream>>>(src, tb, WhT_swz, dst, E, n);
    ushort* tmp = src; src = dst; dst = tmp;
  }

  readout_kernel<<<num_graphs, 256, 0, stream>>>(x_nodes, t_m, src, t4, b_o, WoT1, WoT2,
                                                 (float*)d_out, n, npg, useT4);
}

// Round 2
// 706.099 us; speedup vs baseline: 1.1192x; 1.0565x over previous
//
#include <hip/hip_runtime.h>

// JTNNVAE message-passing net on MI355X — round 6.
// r5 analysis: mp_iter x5 = ~500us of 746 (prologue 153). Both latency-bound, and
// SQ_LDS_BANK_CONFLICT=6.4M revealed the k-XOR swizzle maps 8 lanes/16B-slot on every
// ds_read_b128 (8-way conflict). r6:
// (1) FRAGMENT-MAJOR W_h layout: frag(nf,ks) = contiguous 1KB indexed by lane*16B, both in
//     the global WhF (pre-permuted in prep) and LDS -> every weight read is lane-contiguous,
//     zero bank conflicts, trivial addressing.
// (2) NODE-CENTRIC mp_iter: the 3 pred rows of edge 4u+o are the group's own rows
//     {4u+a, a != o^1}. Each lane owns one row (swapped D-layout, r5-validated), so:
//     G = g[own row]@W (1 MFMA per nf/ks, was 3; 8 loads, was 24), then per f32 value
//     Sa = quad-sum via __shfl_xor(.,2)/(.,1) (DPP) and predsum = Sa - __shfl_xor(G,1).
//     All combines in f32 — no new bf16 rounding.
// (3) grid 512 -> 1024 blocks for chunk-loop load balance.
// ws: WhF 128K | WiT 32K | WoT1 32K | WoT2 128K | tb 102.4M | gA 102.4M | gB 102.4M
// (t3 aliases gB) | optional t4 25.6M.

#define H 256

typedef __attribute__((ext_vector_type(4))) float f32x4;
typedef __attribute__((ext_vector_type(8))) short bf16x8;

#define MFMA(a, b, c) __builtin_amdgcn_mfma_f32_16x16x32_bf16((a), (b), (c), 0, 0, 0)

__device__ __forceinline__ float bf2f(ushort u) {
  union { unsigned int i; float f; } v; v.i = ((unsigned int)u) << 16; return v.f;
}
__device__ __forceinline__ ushort f2bf(float f) {
  union { float f; unsigned int i; } v; v.f = f;
  unsigned int i = v.i;
  i += 0x7fffu + ((i >> 16) & 1u);   // RNE
  return (ushort)(i >> 16);
}

union AFrag { bf16x8 v; ushort u[8]; };

__device__ __forceinline__ int edge_delta(int o) {
  return ((o & 2) ? 5 : 1) * ((o & 1) ? -1 : 1);   // o=0:+1 1:-1 2:+5 3:-5
}

// phi: logical col L -> storage position w (within each 32-col block) so that each lane's
// frag-pair covers 8 contiguous logical cols in the swapped-operand D-layout (r5-validated).
__device__ __forceinline__ int phi(int L) {
  return (L & ~31) | (((L >> 2) & 1) << 4) | (((L >> 3) & 3) << 2) | (L & 3);
}

// ---------------- weight prep ----------------
// WhF fragment-major: halfword idx = ch*32768 + (nf*8+ks)*512 + (kg*16+l15)*8 + i
// holding Wh^T[w = ch*128+nf*16+l15][k = ks*32+kg*8+i], w = phi(logical col).
__global__ __launch_bounds__(256) void prep_weights_kernel(
    const float* __restrict__ Wh, const float* __restrict__ Wi, const float* __restrict__ Wo,
    ushort* __restrict__ WhF, ushort* __restrict__ WiT,
    ushort* __restrict__ WoT1, ushort* __restrict__ WoT2) {
  const int nn = blockIdx.x;   // logical output col 0..255
  const int t = threadIdx.x;   // K index 0..255
  const int w = phi(nn);
  const int ch = w >> 7, nf = (w >> 4) & 7, l15 = w & 15;
  const int ks = t >> 5, kg = (t >> 3) & 3, i = t & 7;
  WhF[ch * 32768 + ((nf * 8 + ks) << 9) + (kg * 16 + l15) * 8 + i] = f2bf(Wh[t * H + nn]);
  WoT2[nn * H + t] = f2bf(Wo[(35 + t) * H + nn]);   // readout unchanged (logical order)
  if (t < 64) {
    WiT[w * 64 + t] = (t < 40) ? f2bf(Wi[t * H + nn]) : (ushort)0;
    WoT1[nn * 64 + t] = (t < 35) ? f2bf(Wo[t * H + nn]) : (ushort)0;
  }
}

// ---------------- sum_tm: t3[4s+o] = sum_{a != o^1} t_m[inc_a(s)], t4[s] = sum_all -------
__global__ __launch_bounds__(256) void sum_tm_kernel(
    const float* __restrict__ t_m, ushort* __restrict__ t3, ushort* __restrict__ t4,
    int n, int useT4) {
  const int idx = blockIdx.x * 256 + threadIdx.x;
  const int s = idx >> 5;             // 32 col-groups of 8 per row
  if (s >= n) return;
  const int cg = (idx & 31) * 8;
  int im1 = s - 1; if (im1 < 0) im1 += n;
  int ip1 = s + 1; if (ip1 >= n) ip1 -= n;
  int im5 = s - 5; if (im5 < 0) im5 += n;
  int ip5 = s + 5; if (ip5 >= n) ip5 -= n;
  const size_t e0 = (size_t)(4 * im1 + 0) * H + cg;
  const size_t e1 = (size_t)(4 * ip1 + 1) * H + cg;
  const size_t e2 = (size_t)(4 * im5 + 2) * H + cg;
  const size_t e3 = (size_t)(4 * ip5 + 3) * H + cg;
  f32x4 v0a = *(const f32x4*)(t_m + e0), v0b = *(const f32x4*)(t_m + e0 + 4);
  f32x4 v1a = *(const f32x4*)(t_m + e1), v1b = *(const f32x4*)(t_m + e1 + 4);
  f32x4 v2a = *(const f32x4*)(t_m + e2), v2b = *(const f32x4*)(t_m + e2 + 4);
  f32x4 v3a = *(const f32x4*)(t_m + e3), v3b = *(const f32x4*)(t_m + e3 + 4);
  f32x4 Sa = v0a + v1a + v2a + v3a;
  f32x4 Sb = v0b + v1b + v2b + v3b;
  f32x4 ra[4] = {Sa - v1a, Sa - v0a, Sa - v3a, Sa - v2a};
  f32x4 rb[4] = {Sb - v1b, Sb - v0b, Sb - v3b, Sb - v2b};
#pragma unroll
  for (int o = 0; o < 4; ++o) {
    AFrag a;
#pragma unroll
    for (int i = 0; i < 4; ++i) { a.u[i] = f2bf(ra[o][i]); a.u[4 + i] = f2bf(rb[o][i]); }
    *(bf16x8*)(t3 + (size_t)(4 * s + o) * H + cg) = a.v;
  }
  if (useT4) {
    AFrag a;
#pragma unroll
    for (int i = 0; i < 4; ++i) { a.u[i] = f2bf(Sa[i]); a.u[4 + i] = f2bf(Sb[i]); }
    *(bf16x8*)(t4 + (size_t)s * H + cg) = a.v;
  }
}

// ---------------- prologue: tb = x_edges@W_i + t3@W_h ; g0P = relu(binput) ---------------
__global__ __launch_bounds__(512, 4) void prologue_kernel(
    const float* __restrict__ x_edges, const ushort* __restrict__ t3,
    const ushort* __restrict__ WhF, const ushort* __restrict__ WiT,
    ushort* __restrict__ tb, ushort* __restrict__ g0P, int E, int n) {
  extern __shared__ ushort lds[];          // 64 frags x 1KB of WhF (64 KB), frag-major
  const int tid = threadIdx.x;
  const int wid = tid >> 6, lane = tid & 63, l15 = lane & 15, kg = lane >> 4;
  const int ch = blockIdx.x >> 9;
  const int colbase = ch << 7;

  {
    const bf16x8* src = (const bf16x8*)(WhF + (size_t)colbase * H);
    bf16x8* dstl = (bf16x8*)lds;
#pragma unroll
    for (int j = 0; j < 8; ++j) dstl[tid + j * 512] = src[tid + j * 512];
  }
  __syncthreads();

  const int nchunks = (E + 127) >> 7;
  for (int c = blockIdx.x & 511; c < nchunks; c += 512) {
    const int row0 = (c << 7) + wid * 16;
    if (row0 >= E) continue;
    const int r = row0 + l15;            // this lane's edge row (swapped D-layout)

    // ---- issue ALL global loads for this chunk up front (MLP) ----
    const float* xp = x_edges + (size_t)r * 40;
    f32x4 xa0 = *(const f32x4*)(xp + kg * 8);
    f32x4 xa1 = *(const f32x4*)(xp + kg * 8 + 4);
    f32x4 xb0, xb1;
    if (kg == 0) { xb0 = *(const f32x4*)(xp + 32); xb1 = *(const f32x4*)(xp + 36); }

    bf16x8 av[8];                        // 8 t3 B-frags in flight across phase X
#pragma unroll
    for (int ks = 0; ks < 8; ++ks)
      av[ks] = *(const bf16x8*)(t3 + (size_t)r * H + ks * 32 + kg * 8);

    f32x4 acc[8];
#pragma unroll
    for (int i = 0; i < 8; ++i) acc[i] = (f32x4){0.f, 0.f, 0.f, 0.f};

    // ---- phase X: binput = x_edges @ W_i, K=40 (padded 64), swapped operands ----
    AFrag bx0, bx1;
#pragma unroll
    for (int i = 0; i < 4; ++i) { bx0.u[i] = f2bf(xa0[i]); bx0.u[4 + i] = f2bf(xa1[i]); }
    if (kg == 0) {
#pragma unroll
      for (int i = 0; i < 4; ++i) { bx1.u[i] = f2bf(xb0[i]); bx1.u[4 + i] = f2bf(xb1[i]); }
    } else {
#pragma unroll
      for (int i = 0; i < 8; ++i) bx1.u[i] = 0;
    }
#pragma unroll
    for (int nf = 0; nf < 8; ++nf) {
      const int w = colbase + nf * 16 + l15;
      bf16x8 a0 = *(const bf16x8*)(WiT + w * 64 + kg * 8);
      acc[nf] = MFMA(a0, bx0.v, acc[nf]);
      bf16x8 a1 = *(const bf16x8*)(WiT + w * 64 + 32 + kg * 8);
      acc[nf] = MFMA(a1, bx1.v, acc[nf]);
    }

    // ---- g0P = relu(binput), permuted row, 4 x 16B stores ----
    const int s_ = r >> 2, o_ = r & 3;
    int d_ = s_ + edge_delta(o_);
    if (d_ < 0) d_ += n; else if (d_ >= n) d_ -= n;
    ushort* gout = g0P + (size_t)(4 * d_ + o_) * H + colbase + kg * 8;
#pragma unroll
    for (int tt = 0; tt < 4; ++tt) {
      AFrag pk;
#pragma unroll
      for (int i = 0; i < 4; ++i) {
        pk.u[i]     = f2bf(fmaxf(acc[2 * tt][i], 0.f));
        pk.u[4 + i] = f2bf(fmaxf(acc[2 * tt + 1][i], 0.f));
      }
      *(bf16x8*)(gout + tt * 32) = pk.v;
    }

    // ---- phase T: += t3 @ W_h (A = frag-major LDS, lane-contiguous reads) ----
#pragma unroll
    for (int ks = 0; ks < 8; ++ks) {
#pragma unroll
      for (int nf = 0; nf < 8; ++nf) {
        bf16x8 a = *(const bf16x8*)(lds + ((nf * 8 + ks) << 9) + (lane << 3));
        acc[nf] = MFMA(a, av[ks], acc[nf]);
      }
    }

    // ---- tb in ORIGINAL edge order, 4 x 16B stores ----
    ushort* tbp = tb + (size_t)r * H + colbase + kg * 8;
#pragma unroll
    for (int tt = 0; tt < 4; ++tt) {
      AFrag pk;
#pragma unroll
      for (int i = 0; i < 4; ++i) {
        pk.u[i]     = f2bf(acc[2 * tt][i]);
        pk.u[4 + i] = f2bf(acc[2 * tt + 1][i]);
      }
      *(bf16x8*)(tbp + tt * 32) = pk.v;
    }
  }
}

// ---------------- loop body: gNewP = relu(tb + sum_preds(gOldP @ W_h)) --------------------
// Node-centric: lane computes G = g[own row]@W (1 MFMA per nf/ks), then
// predsum = quadsum(G) - shfl_xor(G,1)  (dropped row = l15^1 neighbor, same node group).
__global__ __launch_bounds__(512, 4) void mp_iter_kernel(
    const ushort* __restrict__ gOldP, const ushort* __restrict__ tb,
    const ushort* __restrict__ WhF, ushort* __restrict__ gNewP, int E, int n) {
  extern __shared__ ushort lds[];
  const int tid = threadIdx.x;
  const int wid = tid >> 6, lane = tid & 63, l15 = lane & 15, kg = lane >> 4;
  const int ch = blockIdx.x >> 9;
  const int colbase = ch << 7;

  {
    const bf16x8* src = (const bf16x8*)(WhF + (size_t)colbase * H);
    bf16x8* dstl = (bf16x8*)lds;
#pragma unroll
    for (int j = 0; j < 8; ++j) dstl[tid + j * 512] = src[tid + j * 512];
  }
  __syncthreads();

  const int nchunks = (E + 127) >> 7;
  for (int c = blockIdx.x & 511; c < nchunks; c += 512) {
    const int row0 = (c << 7) + wid * 16;
    if (row0 >= E) continue;
    const int r = row0 + l15;            // own stored row; node group = rows r&~3 .. |3

    // ---- all global loads up front: 8 own-row frags + 4 tb frags ----
    bf16x8 av[8];
#pragma unroll
    for (int ks = 0; ks < 8; ++ks)
      av[ks] = *(const bf16x8*)(gOldP + (size_t)r * H + ks * 32 + kg * 8);

    bf16x8 tbv[4];
    const ushort* tbp = tb + (size_t)r * H + colbase + kg * 8;
#pragma unroll
    for (int tt = 0; tt < 4; ++tt) tbv[tt] = *(const bf16x8*)(tbp + tt * 32);

    f32x4 acc[8];
#pragma unroll
    for (int i = 0; i < 8; ++i) acc[i] = (f32x4){0.f, 0.f, 0.f, 0.f};

#pragma unroll
    for (int ks = 0; ks < 8; ++ks) {
#pragma unroll
      for (int nf = 0; nf < 8; ++nf) {
        bf16x8 a = *(const bf16x8*)(lds + ((nf * 8 + ks) << 9) + (lane << 3));
        acc[nf] = MFMA(a, av[ks], acc[nf]);
      }
    }

    const int s = r >> 2, o = r & 3;
    int d = s + edge_delta(o);
    if (d < 0) d += n; else if (d >= n) d -= n;
    ushort* gout = gNewP + (size_t)(4 * d + o) * H + colbase + kg * 8;
#pragma unroll
    for (int tt = 0; tt < 4; ++tt) {
      AFrag pk;
#pragma unroll
      for (int i = 0; i < 4; ++i) {
        const float G0 = acc[2 * tt][i];
        const float G1 = acc[2 * tt + 1][i];
        // quad-sum over node group (lane bits 0,1) + dropped-row fetch (lane^1)
        const float t0 = G0 + __shfl_xor(G0, 2);
        const float S0 = t0 + __shfl_xor(t0, 1);
        const float t1 = G1 + __shfl_xor(G1, 2);
        const float S1 = t1 + __shfl_xor(t1, 1);
        const float d0 = __shfl_xor(G0, 1);
        const float d1 = __shfl_xor(G1, 1);
        const float v0 = bf2f((ushort)tbv[tt][i])     + (S0 - d0);
        const float v1 = bf2f((ushort)tbv[tt][4 + i]) + (S1 - d1);
        pk.u[i]     = f2bf(fmaxf(v0, 0.f));
        pk.u[4 + i] = f2bf(fmaxf(v1, 0.f));
      }
      *(bf16x8*)(gout + tt * 32) = pk.v;
    }
  }
}

// ---------------- readout: per-graph mean of relu([x_nodes, nei]@W_o + b_o) ---------------
__global__ __launch_bounds__(256) void readout_kernel(
    const float* __restrict__ x_nodes, const float* __restrict__ t_m,
    const ushort* __restrict__ gP, const ushort* __restrict__ t4,
    const float* __restrict__ b_o,
    const ushort* __restrict__ WoT1, const ushort* __restrict__ WoT2,
    float* __restrict__ out, int n, int npg, int useT4) {
  const int gidx = blockIdx.x;
  const int wid = threadIdx.x >> 6;
  const int lane = threadIdx.x & 63;
  const int l15 = lane & 15;
  const int kg = lane >> 4;
  const int u0 = gidx * npg;

  __shared__ float red[H];

  f32x4 acc[2][16];
#pragma unroll
  for (int m = 0; m < 2; ++m)
#pragma unroll
    for (int i = 0; i < 16; ++i) acc[m][i] = (f32x4){0.f, 0.f, 0.f, 0.f};

  int uu[2]; bool mv[2]; int inc[2][4];
#pragma unroll
  for (int m = 0; m < 2; ++m) {
    const int mf = wid * 2 + m;
    const int rl = mf * 16 + l15;
    mv[m] = rl < npg;
    const int u = u0 + rl;
    uu[m] = u;
    if (mv[m]) {
      inc[m][0] = 4 * ((u - 1 + n) % n);
      inc[m][1] = 4 * ((u + 1) % n) + 1;
      inc[m][2] = 4 * ((u - 5 + n) % n) + 2;
      inc[m][3] = 4 * ((u + 5) % n) + 3;
    } else {
      inc[m][0] = inc[m][1] = inc[m][2] = inc[m][3] = 0;
    }
  }

  // phase 1: x_nodes part, K=35 (padded 64)
#pragma unroll
  for (int ks = 0; ks < 2; ++ks) {
    const int k = ks * 32 + kg * 8;
#pragma unroll
    for (int m = 0; m < 2; ++m) {
      AFrag a;
#pragma unroll
      for (int i = 0; i < 8; ++i) {
        const int kk = k + i;
        a.u[i] = (mv[m] && kk < 35) ? f2bf(x_nodes[(size_t)uu[m] * 35 + kk]) : (ushort)0;
      }
#pragma unroll
      for (int nf = 0; nf < 16; ++nf) {
        bf16x8 b = *(const bf16x8*)(WoT1 + (nf * 16 + l15) * 64 + k);
        acc[m][nf] = MFMA(a.v, b, acc[m][nf]);
      }
    }
  }

  // phase 2: nei part, K=256.  nei[u] = sum_j gP[4u+j] + (t4[u] | sum_j t_m[inc_j(u)])
#pragma unroll
  for (int ks = 0; ks < 8; ++ks) {
    const int k = ks * 32 + kg * 8;
#pragma unroll
    for (int m = 0; m < 2; ++m) {
      AFrag a;
      if (mv[m]) {
        float s[8];
#pragma unroll
        for (int i = 0; i < 8; ++i) s[i] = 0.f;
        const int e4 = 4 * uu[m];
#pragma unroll
        for (int j = 0; j < 4; ++j) {
          bf16x8 gv = *(const bf16x8*)(gP + (size_t)(e4 + j) * H + k);
#pragma unroll
          for (int i = 0; i < 8; ++i) s[i] += bf2f((ushort)gv[i]);
        }
        if (useT4) {
          bf16x8 tv = *(const bf16x8*)(t4 + (size_t)uu[m] * H + k);
#pragma unroll
          for (int i = 0; i < 8; ++i) s[i] += bf2f((ushort)tv[i]);
        } else {
#pragma unroll
          for (int j = 0; j < 4; ++j) {
            const float* tp = t_m + (size_t)inc[m][j] * H + k;
            f32x4 t0 = *(const f32x4*)tp;
            f32x4 t1 = *(const f32x4*)(tp + 4);
#pragma unroll
            for (int i = 0; i < 4; ++i) { s[i] += t0[i]; s[4 + i] += t1[i]; }
          }
        }
#pragma unroll
        for (int i = 0; i < 8; ++i) a.u[i] = f2bf(s[i]);
      } else {
#pragma unroll
        for (int i = 0; i < 8; ++i) a.u[i] = 0;
      }
#pragma unroll
      for (int nf = 0; nf < 16; ++nf) {
        bf16x8 b = *(const bf16x8*)(WoT2 + (nf * 16 + l15) * H + k);
        acc[m][nf] = MFMA(a.v, b, acc[m][nf]);
      }
    }
  }

  red[threadIdx.x] = 0.f;
  __syncthreads();

#pragma unroll
  for (int nf = 0; nf < 16; ++nf) {
    const int col = nf * 16 + l15;
    const float bias = b_o[col];
    float cs = 0.f;
#pragma unroll
    for (int m = 0; m < 2; ++m) {
#pragma unroll
      for (int j = 0; j < 4; ++j) {
        const int rr = (wid * 2 + m) * 16 + kg * 4 + j;
        if (rr < npg) cs += fmaxf(acc[m][nf][j] + bias, 0.f);
      }
    }
    cs += __shfl_xor(cs, 16);
    cs += __shfl_xor(cs, 32);
    if (kg == 0) atomicAdd(&red[col], cs);
  }
  __syncthreads();
  out[(size_t)gidx * H + threadIdx.x] = red[threadIdx.x] * (1.0f / (float)npg);
}

// ------------------------------------- launch ---------------------------------------------
extern "C" void kernel_launch(void* const* d_in, const int* in_sizes, int n_in,
                              void* d_out, int out_size, void* d_ws, size_t ws_size,
                              hipStream_t stream) {
  const float* x_nodes = (const float*)d_in[0];
  const float* x_edges = (const float*)d_in[1];
  const float* t_m     = (const float*)d_in[2];
  const float* W_i     = (const float*)d_in[3];
  const float* W_h     = (const float*)d_in[4];
  const float* W_o     = (const float*)d_in[5];
  const float* b_o     = (const float*)d_in[6];
  (void)n_in;

  const int n = in_sizes[0] / 35;       // 50000
  const int E = in_sizes[1] / 40;       // 200000
  const int num_graphs = out_size / H;  // 500
  const int npg = n / num_graphs;       // 100

  char* ws = (char*)d_ws;
  ushort* WhF  = (ushort*)(ws);                 // 131072 B (fragment-major)
  ushort* WiT  = (ushort*)(ws + 131072);        // 32768 B
  ushort* WoT1 = (ushort*)(ws + 164 * 1024);    // 32768 B
  ushort* WoT2 = (ushort*)(ws + 200 * 1024);    // 131072 B
  size_t off = 336 * 1024;
  const size_t gbytes = (size_t)E * H * 2;      // 102,400,000
  ushort* tb = (ushort*)(ws + off); off += gbytes;
  ushort* gA = (ushort*)(ws + off); off += gbytes;
  ushort* gB = (ushort*)(ws + off); off += gbytes;
  ushort* t3 = gB;   // t3 only needed until the first mp_iter overwrites gB
  const size_t t4bytes = (size_t)n * H * 2;     // 25,600,000
  const int useT4 = (ws_size >= off + t4bytes) ? 1 : 0;
  ushort* t4 = (ushort*)(ws + off);             // valid only if useT4

  prep_weights_kernel<<<256, 256, 0, stream>>>(W_h, W_i, W_o, WhF, WiT, WoT1, WoT2);
  sum_tm_kernel<<<(n * 32 + 255) / 256, 256, 0, stream>>>(t_m, t3, t4, n, useT4);
  prologue_kernel<<<1024, 512, 65536, stream>>>(x_edges, t3, WhF, WiT, tb, gA, E, n);

  ushort* src = gA;
  ushort* dst = gB;
  for (int it = 0; it < 5; ++it) {  // DEPTH-1 = 5
    mp_iter_kernel<<<1024, 512, 65536, stream>>>(src, tb, WhF, dst, E, n);
    ushort* tmp = src; src = dst; dst = tmp;
  }

  readout_kernel<<<num_graphs, 256, 0, stream>>>(x_nodes, t_m, src, t4, b_o, WoT1, WoT2,
                                                 (float*)d_out, n, npg, useT4);
}